// Round 7
// baseline (57.003 us; speedup 1.0000x reference)
//
#include <hip/hip_runtime.h>

#define NPIX 5184   // 72*72
#define KDIM 256
#define OUTHW 224
#define BM 128
#define BN 128
#define NTT 42          // 5376/128
#define NPAD (NTT*BM)   // 5376 padded rows
#define NWG (NTT*NTT)   // 1764
#define MATB (128*128)  // 16 KiB: 128 rows x 64 bf16 (128 B)
#define BUFB (2*MATB)   // 32 KiB per double-buffer slot (A+B)

typedef __bf16 bf16x8 __attribute__((ext_vector_type(8)));
typedef float  f32x4  __attribute__((ext_vector_type(4)));

__device__ inline unsigned short f2bf(float f) {
    unsigned int b = __float_as_uint(f);
    b += 0x7FFFu + ((b >> 16) & 1u);     // round-to-nearest-even
    return (unsigned short)(b >> 16);
}
// monotonic float<->uint mapping so atomicMax(uint) orders floats
__device__ inline unsigned int fmono(float f) {
    unsigned int b = __float_as_uint(f);
    return b ^ ((b >> 31) ? 0xFFFFFFFFu : 0x80000000u);
}
__device__ inline float funmono(unsigned int u) {
    unsigned int b = u ^ ((u >> 31) ? 0x80000000u : 0xFFFFFFFFu);
    return __uint_as_float(b);
}

// fp32 -> bf16 with zero-padding to NPAD rows; also inits sums and max.
__global__ void convert_pad_bf16(const float* __restrict__ x,
                                 unsigned short* __restrict__ Abf,
                                 unsigned short* __restrict__ Bbf,
                                 float* __restrict__ sums,
                                 unsigned int* __restrict__ max_u) {
    int i = blockIdx.x * blockDim.x + threadIdx.x;   // one 8-elem chunk
    if (i < 2 * NPAD) sums[i] = 0.0f;
    if (i == 0) *max_u = 0u;
    const int CPM = NPAD * (KDIM / 8);               // chunks per matrix
    if (i >= 2 * CPM) return;
    int mat = i / CPM;
    int rem = i - mat * CPM;
    int row = rem >> 5;          // KDIM/8 = 32 chunks per row
    int c8  = rem & 31;
    ushort4 lo = {0, 0, 0, 0}, hi = {0, 0, 0, 0};
    if (row < NPIX) {
        const float* src = x + (size_t)mat * NPIX * KDIM + (size_t)row * KDIM + c8 * 8;
        float4 v0 = reinterpret_cast<const float4*>(src)[0];
        float4 v1 = reinterpret_cast<const float4*>(src)[1];
        lo = ushort4{ f2bf(v0.x), f2bf(v0.y), f2bf(v0.z), f2bf(v0.w) };
        hi = ushort4{ f2bf(v1.x), f2bf(v1.y), f2bf(v1.z), f2bf(v1.w) };
    }
    unsigned short* d = (mat ? Bbf : Abf) + (size_t)row * KDIM + c8 * 8;
    reinterpret_cast<ushort4*>(d)[0] = lo;
    reinterpret_cast<ushort4*>(d)[1] = hi;
}

// D = A*B^T (5376^2 padded, K=256), 128x128 tiles, 4 waves (2x2) each 64x64.
// acc[4][4] = 64 AGPR -> ~170 total regs, far under the 256/thread cap at
// 2 waves/SIMD: NO spill (R4/R5 lesson: acc[8][4]=128 AGPR left only 128
// arch VGPRs -> 19MB scratch traffic). 64KB LDS dbuf -> 2 blocks/CU for
// cross-block latency hiding. Staging/epilogue structure = R5 (verified).
__global__ __launch_bounds__(256, 2) void gemm_reduce(
        const unsigned short* __restrict__ Abf, const unsigned short* __restrict__ Bbf,
        float* __restrict__ row_sum, float* __restrict__ col_sum,
        unsigned int* __restrict__ max_u) {
    __shared__ char lds[2 * BUFB];        // 64 KiB

    const int tid  = threadIdx.x;
    const int wave = tid >> 6, lane = tid & 63;

    // bijective XCD chunk swizzle (1764 = 8*220 + 4)
    const int wg = blockIdx.x;
    const int q = NWG >> 3, r8 = NWG & 7;
    const int xcd = wg & 7, cidx = wg >> 3;
    const int swz = (xcd < r8) ? xcd * (q + 1) + cidx
                               : r8 * (q + 1) + (xcd - r8) * q + cidx;
    const int brow = (swz / NTT) * BM;
    const int bcol = (swz % NTT) * BN;

    const char* Ag = (const char*)Abf;
    const char* Bg = (const char*)Bbf;

    // stage K-tile t into buffer d: 8 global_load_lds(16B)/thread = 32 KB
    // LDS swizzle: 16B chunk c of row r at slot c^(r&7).
    auto stage = [&](int t, int d) {
        char* Ab = lds + d * BUFB;
        char* Bb = Ab + MATB;
        #pragma unroll
        for (int j = 0; j < 4; ++j) {
            int base = wave * 4096 + j * 1024;       // wave-uniform LDS dest
            int p    = base + lane * 16;
            int row  = p >> 7;                       // 128 B per row
            int c    = ((p >> 4) & 7) ^ (row & 7);   // pre-swizzled src chunk
            __builtin_amdgcn_global_load_lds(
                (const __attribute__((address_space(1))) unsigned int*)
                    (Ag + (size_t)(brow + row) * 512 + t * 128 + (c << 4)),
                (__attribute__((address_space(3))) unsigned int*)(Ab + base),
                16, 0, 0);
            __builtin_amdgcn_global_load_lds(
                (const __attribute__((address_space(1))) unsigned int*)
                    (Bg + (size_t)(bcol + row) * 512 + t * 128 + (c << 4)),
                (__attribute__((address_space(3))) unsigned int*)(Bb + base),
                16, 0, 0);
        }
    };

    stage(0, 0);
    __syncthreads();                      // drains vmcnt(0)

    const int wr = wave >> 1;   // 0..1  -> m block of 64 rows
    const int wc = wave & 1;    // 0..1  -> n block of 64 cols
    const int lr = lane & 15;
    const int lg = lane >> 4;   // 0..3

    f32x4 acc[4][4] = {};
    #pragma unroll
    for (int t = 0; t < 4; ++t) {
        if (t + 1 < 4) stage(t + 1, (t + 1) & 1);   // issue early (T14)
        const char* Ab = lds + (t & 1) * BUFB;
        const char* Bb = Ab + MATB;
        #pragma unroll
        for (int ksl = 0; ksl < 2; ++ksl) {
            int kc = ksl * 4 + lg;
            bf16x8 a[4], b[4];
            #pragma unroll
            for (int m = 0; m < 4; ++m) {
                int r = wr * 64 + m * 16 + lr;
                a[m] = *reinterpret_cast<const bf16x8*>(Ab + r * 128 + ((kc ^ (r & 7)) << 4));
            }
            #pragma unroll
            for (int n = 0; n < 4; ++n) {
                int r = wc * 64 + n * 16 + lr;
                b[n] = *reinterpret_cast<const bf16x8*>(Bb + r * 128 + ((kc ^ (r & 7)) << 4));
            }
            #pragma unroll
            for (int m = 0; m < 4; ++m)
                #pragma unroll
                for (int n = 0; n < 4; ++n)
                    acc[m][n] = __builtin_amdgcn_mfma_f32_16x16x32_bf16(a[m], b[n], acc[m][n], 0, 0, 0);
        }
        __syncthreads();        // retires buf reads + drains stage(t+1)
    }

    // ---- fused reductions. C/D: col = lane&15, row = (lane>>4)*4 + reg ----
    float mx = -3.4e38f;
    float cs[4] = {0.f, 0.f, 0.f, 0.f};
    float rs[16];
    #pragma unroll
    for (int j = 0; j < 16; ++j) rs[j] = 0.0f;
    #pragma unroll
    for (int m = 0; m < 4; ++m)
        #pragma unroll
        for (int n = 0; n < 4; ++n)
            #pragma unroll
            for (int r = 0; r < 4; ++r) {
                float v = acc[m][n][r];
                mx = fmaxf(mx, v);
                float rv = fmaxf(v, 0.0f);
                cs[n] += rv;
                rs[m * 4 + r] += rv;
            }

    // col sums: reduce over lane groups (rows); lanes 0..15 hold cols
    #pragma unroll
    for (int n = 0; n < 4; ++n) {
        cs[n] += __shfl_xor(cs[n], 16);
        cs[n] += __shfl_xor(cs[n], 32);
    }
    if (lane < 16) {
        #pragma unroll
        for (int n = 0; n < 4; ++n)
            atomicAdd(&col_sum[bcol + wc * 64 + n * 16 + lane], cs[n]);
    }

    // row sums: butterfly across the 16 col-lanes within each lane group
    #pragma unroll
    for (int off = 1; off <= 8; off <<= 1)
        #pragma unroll
        for (int j = 0; j < 16; ++j)
            rs[j] += __shfl_xor(rs[j], off);
    if (lr == 0) {
        int rbase = brow + wr * 64 + lg * 4;
        #pragma unroll
        for (int m = 0; m < 4; ++m)
            #pragma unroll
            for (int r = 0; r < 4; ++r)
                atomicAdd(&row_sum[rbase + m * 16 + r], rs[m * 4 + r]);
    }

    // block max -> one atomicMax
    #pragma unroll
    for (int off = 32; off >= 1; off >>= 1)
        mx = fmaxf(mx, __shfl_xor(mx, off));
    float* smax = reinterpret_cast<float*>(lds);
    if (lane == 0) smax[wave] = mx;
    __syncthreads();
    if (tid == 0) {
        float m4 = fmaxf(fmaxf(smax[0], smax[1]), fmaxf(smax[2], smax[3]));
        atomicMax(max_u, fmono(m4));
    }
}

// Bilinear resize 2x72x72 -> 2x224x224 with final /max (resize is linear).
__global__ void finalize(const float* __restrict__ row_sum,
                         const float* __restrict__ col_sum,
                         const unsigned int* __restrict__ max_u,
                         float* __restrict__ out) {
    int o = blockIdx.x * blockDim.x + threadIdx.x;
    if (o >= 2 * OUTHW * OUTHW) return;
    int img = o / (OUTHW * OUTHW);
    int rem = o % (OUTHW * OUTHW);
    int oy = rem / OUTHW, ox = rem % OUTHW;
    const float* src = (img == 0) ? row_sum : col_sum;
    float inv = 1.0f / funmono(*max_u);

    const float s = 72.0f / 224.0f;
    float ys = fmaxf(((float)oy + 0.5f) * s - 0.5f, 0.0f);
    float xs = fmaxf(((float)ox + 0.5f) * s - 0.5f, 0.0f);
    int y0 = (int)floorf(ys), x0 = (int)floorf(xs);
    int y1 = min(y0 + 1, 71), x1 = min(x0 + 1, 71);
    float wy = ys - (float)y0, wx = xs - (float)x0;

    float a = src[y0 * 72 + x0], b = src[y0 * 72 + x1];
    float c = src[y1 * 72 + x0], d = src[y1 * 72 + x1];
    float v = a * (1.0f - wy) * (1.0f - wx) + b * (1.0f - wy) * wx
            + c * wy * (1.0f - wx)          + d * wy * wx;
    out[o] = v * inv;
}

extern "C" void kernel_launch(void* const* d_in, const int* in_sizes, int n_in,
                              void* d_out, int out_size, void* d_ws, size_t ws_size,
                              hipStream_t stream) {
    const float* X = (const float*)d_in[0];
    float* out = (float*)d_out;

    unsigned short* Abf = (unsigned short*)d_ws;
    unsigned short* Bbf = Abf + (size_t)NPAD * KDIM;
    float* row_sum      = (float*)(Bbf + (size_t)NPAD * KDIM);
    float* col_sum      = row_sum + NPAD;   // contiguous: convert inits both
    unsigned int* max_u = (unsigned int*)(col_sum + NPAD);

    int nthr = 2 * NPAD * (KDIM / 8);
    convert_pad_bf16<<<(nthr + 255) / 256, 256, 0, stream>>>(X, Abf, Bbf, row_sum, max_u);
    gemm_reduce<<<NWG, 256, 0, stream>>>(Abf, Bbf, row_sum, col_sum, max_u);
    finalize<<<(2 * OUTHW * OUTHW + 255) / 256, 256, 0, stream>>>(row_sum, col_sum, max_u, out);
}

// Round 8
// 53.133 us; speedup vs baseline: 1.0728x; 1.0728x over previous
//
#include <hip/hip_runtime.h>

#define NPIX 5184   // 72*72
#define KDIM 256
#define OUTHW 224
#define BM 128
#define NTT 42          // 5376/128
#define NPAD (NTT*BM)   // 5376 padded rows
#define NWG (NTT*NTT)   // 1764
#define MATB 8192       // 8 KiB: 128 rows x 32 bf16 (64 B)
#define BUFB (2*MATB)   // 16 KiB per double-buffer slot (A+B)
#define NKT 8           // K=256 in chunks of 32

typedef __bf16 bf16x8 __attribute__((ext_vector_type(8)));
typedef float  f32x4  __attribute__((ext_vector_type(4)));

__device__ inline unsigned short f2bf(float f) {
    unsigned int b = __float_as_uint(f);
    b += 0x7FFFu + ((b >> 16) & 1u);     // round-to-nearest-even
    return (unsigned short)(b >> 16);
}
// monotonic float<->uint mapping so atomicMax(uint) orders floats
__device__ inline unsigned int fmono(float f) {
    unsigned int b = __float_as_uint(f);
    return b ^ ((b >> 31) ? 0xFFFFFFFFu : 0x80000000u);
}
__device__ inline float funmono(unsigned int u) {
    unsigned int b = u ^ ((u >> 31) ? 0x80000000u : 0xFFFFFFFFu);
    return __uint_as_float(b);
}

// fp32 -> bf16 with zero-padding to NPAD rows; also inits sums and max.
__global__ void convert_pad_bf16(const float* __restrict__ x,
                                 unsigned short* __restrict__ Abf,
                                 unsigned short* __restrict__ Bbf,
                                 float* __restrict__ sums,
                                 unsigned int* __restrict__ max_u) {
    int i = blockIdx.x * blockDim.x + threadIdx.x;   // one 8-elem chunk
    if (i < 2 * NPAD) sums[i] = 0.0f;
    if (i == 0) *max_u = 0u;
    const int CPM = NPAD * (KDIM / 8);               // chunks per matrix
    if (i >= 2 * CPM) return;
    int mat = i / CPM;
    int rem = i - mat * CPM;
    int row = rem >> 5;          // KDIM/8 = 32 chunks per row
    int c8  = rem & 31;
    ushort4 lo = {0, 0, 0, 0}, hi = {0, 0, 0, 0};
    if (row < NPIX) {
        const float* src = x + (size_t)mat * NPIX * KDIM + (size_t)row * KDIM + c8 * 8;
        float4 v0 = reinterpret_cast<const float4*>(src)[0];
        float4 v1 = reinterpret_cast<const float4*>(src)[1];
        lo = ushort4{ f2bf(v0.x), f2bf(v0.y), f2bf(v0.z), f2bf(v0.w) };
        hi = ushort4{ f2bf(v1.x), f2bf(v1.y), f2bf(v1.z), f2bf(v1.w) };
    }
    unsigned short* d = (mat ? Bbf : Abf) + (size_t)row * KDIM + c8 * 8;
    reinterpret_cast<ushort4*>(d)[0] = lo;
    reinterpret_cast<ushort4*>(d)[1] = hi;
}

// D = A*B^T (5376^2 padded, K=256), 128x128 tiles, 4 waves (2x2) each 64x64.
// BK=32 -> 32 KiB LDS total (dbuf) -> 3-4 blocks/CU co-resident: independent
// blocks at staggered phases hide ds_read latency + barrier drains (the
// R2-R7 plateau at ~300 TF was 1-2 phase-locked blocks/CU with 1 wave/SIMD).
// One barrier per K-tile (m97 pattern): barrier; stage(t+1); compute(t).
// LDS swizzle: 16B chunk c of row r at slot c^((r>>1)&3) -> 2-way max (free).
__global__ __launch_bounds__(256, 3) void gemm_reduce(
        const unsigned short* __restrict__ Abf, const unsigned short* __restrict__ Bbf,
        float* __restrict__ row_sum, float* __restrict__ col_sum,
        unsigned int* __restrict__ max_u) {
    __shared__ char lds[2 * BUFB];        // 32 KiB

    const int tid  = threadIdx.x;
    const int wave = tid >> 6, lane = tid & 63;

    // bijective XCD chunk swizzle (1764 = 8*220 + 4)
    const int wg = blockIdx.x;
    const int q = NWG >> 3, r8 = NWG & 7;
    const int xcd = wg & 7, cidx = wg >> 3;
    const int swz = (xcd < r8) ? xcd * (q + 1) + cidx
                               : r8 * (q + 1) + (xcd - r8) * q + cidx;
    const int brow = (swz / NTT) * BM;
    const int bcol = (swz % NTT) * BM;

    // ---- hoisted stage addressing (invariant across j and t):
    // lane position p -> row 0..127 (j adds 16 rows = +8192B global, +1024B LDS;
    // t adds +64B global). Swizzle key (row>>1)&3 is invariant to row+=16.
    const int p     = wave * 2048 + lane * 16;
    const int srow  = p >> 6;
    const int schk  = ((p >> 4) & 3) ^ ((srow >> 1) & 3);
    const char* gAp = (const char*)Abf + (size_t)(brow + srow) * 512 + (schk << 4);
    const char* gBp = (const char*)Bbf + (size_t)(bcol + srow) * 512 + (schk << 4);

#define GLDS(gp, lp) __builtin_amdgcn_global_load_lds( \
    (const __attribute__((address_space(1))) unsigned int*)(gp), \
    (__attribute__((address_space(3))) unsigned int*)(lp), 16, 0, 0)

    // stage K-tile T into buffer T&1: 4 x 16B per thread (A j0,j1; B j0,j1)
#define STAGE(T) {                                                      \
    char* db_ = lds + ((T) & 1) * BUFB + wave * 2048;                   \
    GLDS(gAp + (T) * 64,        db_);                                   \
    GLDS(gAp + (T) * 64 + 8192, db_ + 1024);                            \
    GLDS(gBp + (T) * 64,        db_ + MATB);                            \
    GLDS(gBp + (T) * 64 + 8192, db_ + MATB + 1024);                     \
}

    const int wr = wave >> 1;   // 0..1  -> m block of 64 rows
    const int wc = wave & 1;    // 0..1  -> n block of 64 cols
    const int lr = lane & 15;
    const int lg = lane >> 4;   // 0..3 = K chunk (8 bf16 each)

    // hoisted LDS read offsets (swizzle folded)
    int aoff[4], boff[4];
    #pragma unroll
    for (int m = 0; m < 4; ++m) {
        int r = wr * 64 + m * 16 + lr;
        aoff[m] = r * 64 + ((lg ^ ((r >> 1) & 3)) << 4);
    }
    #pragma unroll
    for (int n = 0; n < 4; ++n) {
        int r = wc * 64 + n * 16 + lr;
        boff[n] = MATB + r * 64 + ((lg ^ ((r >> 1) & 3)) << 4);
    }

    f32x4 acc[4][4] = {};

    STAGE(0);
    #pragma unroll
    for (int t = 0; t < NKT; ++t) {
        __syncthreads();                 // drains stage(t); reads of buf[(t+1)&1] retired
        if (t + 1 < NKT) STAGE(t + 1);   // issue early; hides under compute(t)
        const char* base = lds + (t & 1) * BUFB;
        bf16x8 a[4], b[4];
        #pragma unroll
        for (int m = 0; m < 4; ++m)
            a[m] = *reinterpret_cast<const bf16x8*>(base + aoff[m]);
        #pragma unroll
        for (int n = 0; n < 4; ++n)
            b[n] = *reinterpret_cast<const bf16x8*>(base + boff[n]);
        #pragma unroll
        for (int m = 0; m < 4; ++m)
            #pragma unroll
            for (int n = 0; n < 4; ++n)
                acc[m][n] = __builtin_amdgcn_mfma_f32_16x16x32_bf16(a[m], b[n], acc[m][n], 0, 0, 0);
    }
#undef GLDS
#undef STAGE

    // ---- fused reductions. C/D: col = lane&15, row = (lane>>4)*4 + reg ----
    float mx = -3.4e38f;
    float cs[4] = {0.f, 0.f, 0.f, 0.f};
    float rs[16];
    #pragma unroll
    for (int j = 0; j < 16; ++j) rs[j] = 0.0f;
    #pragma unroll
    for (int m = 0; m < 4; ++m)
        #pragma unroll
        for (int n = 0; n < 4; ++n)
            #pragma unroll
            for (int r = 0; r < 4; ++r) {
                float v = acc[m][n][r];
                mx = fmaxf(mx, v);
                float rv = fmaxf(v, 0.0f);
                cs[n] += rv;
                rs[m * 4 + r] += rv;
            }

    // col sums: reduce over lane groups (rows); lanes 0..15 hold cols
    #pragma unroll
    for (int n = 0; n < 4; ++n) {
        cs[n] += __shfl_xor(cs[n], 16);
        cs[n] += __shfl_xor(cs[n], 32);
    }
    if (lane < 16) {
        #pragma unroll
        for (int n = 0; n < 4; ++n)
            atomicAdd(&col_sum[bcol + wc * 64 + n * 16 + lane], cs[n]);
    }

    // row sums: butterfly across the 16 col-lanes within each lane group
    #pragma unroll
    for (int off = 1; off <= 8; off <<= 1)
        #pragma unroll
        for (int j = 0; j < 16; ++j)
            rs[j] += __shfl_xor(rs[j], off);
    if (lr == 0) {
        int rbase = brow + wr * 64 + lg * 4;
        #pragma unroll
        for (int m = 0; m < 4; ++m)
            #pragma unroll
            for (int r = 0; r < 4; ++r)
                atomicAdd(&row_sum[rbase + m * 16 + r], rs[m * 4 + r]);
    }

    // block max -> one atomicMax (LDS reuse only after all reads retired)
    #pragma unroll
    for (int off = 32; off >= 1; off >>= 1)
        mx = fmaxf(mx, __shfl_xor(mx, off));
    __syncthreads();
    float* smax = reinterpret_cast<float*>(lds);
    if (lane == 0) smax[wave] = mx;
    __syncthreads();
    if (tid == 0) {
        float m4 = fmaxf(fmaxf(smax[0], smax[1]), fmaxf(smax[2], smax[3]));
        atomicMax(max_u, fmono(m4));
    }
}

// Bilinear resize 2x72x72 -> 2x224x224 with final /max (resize is linear).
__global__ void finalize(const float* __restrict__ row_sum,
                         const float* __restrict__ col_sum,
                         const unsigned int* __restrict__ max_u,
                         float* __restrict__ out) {
    int o = blockIdx.x * blockDim.x + threadIdx.x;
    if (o >= 2 * OUTHW * OUTHW) return;
    int img = o / (OUTHW * OUTHW);
    int rem = o % (OUTHW * OUTHW);
    int oy = rem / OUTHW, ox = rem % OUTHW;
    const float* src = (img == 0) ? row_sum : col_sum;
    float inv = 1.0f / funmono(*max_u);

    const float s = 72.0f / 224.0f;
    float ys = fmaxf(((float)oy + 0.5f) * s - 0.5f, 0.0f);
    float xs = fmaxf(((float)ox + 0.5f) * s - 0.5f, 0.0f);
    int y0 = (int)floorf(ys), x0 = (int)floorf(xs);
    int y1 = min(y0 + 1, 71), x1 = min(x0 + 1, 71);
    float wy = ys - (float)y0, wx = xs - (float)x0;

    float a = src[y0 * 72 + x0], b = src[y0 * 72 + x1];
    float c = src[y1 * 72 + x0], d = src[y1 * 72 + x1];
    float v = a * (1.0f - wy) * (1.0f - wx) + b * (1.0f - wy) * wx
            + c * wy * (1.0f - wx)          + d * wy * wx;
    out[o] = v * inv;
}

extern "C" void kernel_launch(void* const* d_in, const int* in_sizes, int n_in,
                              void* d_out, int out_size, void* d_ws, size_t ws_size,
                              hipStream_t stream) {
    const float* X = (const float*)d_in[0];
    float* out = (float*)d_out;

    unsigned short* Abf = (unsigned short*)d_ws;
    unsigned short* Bbf = Abf + (size_t)NPAD * KDIM;
    float* row_sum      = (float*)(Bbf + (size_t)NPAD * KDIM);
    float* col_sum      = row_sum + NPAD;   // contiguous: convert inits both
    unsigned int* max_u = (unsigned int*)(col_sum + NPAD);

    int nthr = 2 * NPAD * (KDIM / 8);
    convert_pad_bf16<<<(nthr + 255) / 256, 256, 0, stream>>>(X, Abf, Bbf, row_sum, max_u);
    gemm_reduce<<<NWG, 256, 0, stream>>>(Abf, Bbf, row_sum, col_sum, max_u);
    finalize<<<(2 * OUTHW * OUTHW + 255) / 256, 256, 0, stream>>>(row_sum, col_sum, max_u, out);
}

// Round 9
// 40.104 us; speedup vs baseline: 1.4214x; 1.3249x over previous
//
#include <hip/hip_runtime.h>

#define NPIX 5184   // 72*72
#define KDIM 256
#define OUTHW 224
#define BM 128
#define NTT 42          // 5376/128
#define NPAD (NTT*BM)   // 5376 padded rows
#define NWG (NTT*NTT)   // 1764
#define MATB 8192       // 8 KiB: 128 rows x 32 bf16 (64 B)
#define BUFB (2*MATB)   // 16 KiB per double-buffer slot (A+B)
#define NKT 8           // K=256 in chunks of 32

typedef __bf16 bf16x8 __attribute__((ext_vector_type(8)));
typedef float  f32x4  __attribute__((ext_vector_type(4)));

__device__ inline unsigned short f2bf(float f) {
    unsigned int b = __float_as_uint(f);
    b += 0x7FFFu + ((b >> 16) & 1u);     // round-to-nearest-even
    return (unsigned short)(b >> 16);
}

// fp32 -> bf16 with zero-padding to NPAD rows.
__global__ void convert_pad_bf16(const float* __restrict__ x,
                                 unsigned short* __restrict__ Abf,
                                 unsigned short* __restrict__ Bbf) {
    int i = blockIdx.x * blockDim.x + threadIdx.x;   // one 8-elem chunk
    const int CPM = NPAD * (KDIM / 8);               // chunks per matrix
    if (i >= 2 * CPM) return;
    int mat = i / CPM;
    int rem = i - mat * CPM;
    int row = rem >> 5;          // KDIM/8 = 32 chunks per row
    int c8  = rem & 31;
    ushort4 lo = {0, 0, 0, 0}, hi = {0, 0, 0, 0};
    if (row < NPIX) {
        const float* src = x + (size_t)mat * NPIX * KDIM + (size_t)row * KDIM + c8 * 8;
        float4 v0 = reinterpret_cast<const float4*>(src)[0];
        float4 v1 = reinterpret_cast<const float4*>(src)[1];
        lo = ushort4{ f2bf(v0.x), f2bf(v0.y), f2bf(v0.z), f2bf(v0.w) };
        hi = ushort4{ f2bf(v1.x), f2bf(v1.y), f2bf(v1.z), f2bf(v1.w) };
    }
    unsigned short* d = (mat ? Bbf : Abf) + (size_t)row * KDIM + c8 * 8;
    reinterpret_cast<ushort4*>(d)[0] = lo;
    reinterpret_cast<ushort4*>(d)[1] = hi;
}

// D = A*B^T (5376^2 padded, K=256), 128x128 tiles, 4 waves (2x2) each 64x64.
// Staging/compute = R8 verbatim (verified). Epilogue: NO ATOMICS — partial
// row/col sums go through LDS to disjoint ws slots; a tiny second kernel
// folds them. (R1-R8 all pinned at ~1.3 device-scope atomic ops/cy; this
// round isolates that as the suspected ceiling.)
__global__ __launch_bounds__(256, 3) void gemm_reduce(
        const unsigned short* __restrict__ Abf, const unsigned short* __restrict__ Bbf,
        float* __restrict__ partial_row, float* __restrict__ partial_col,
        float* __restrict__ blk_max) {
    __shared__ char lds[2 * BUFB];        // 32 KiB

    const int tid  = threadIdx.x;
    const int wave = tid >> 6, lane = tid & 63;

    // bijective XCD chunk swizzle (1764 = 8*220 + 4)
    const int wg = blockIdx.x;
    const int q = NWG >> 3, r8 = NWG & 7;
    const int xcd = wg & 7, cidx = wg >> 3;
    const int swz = (xcd < r8) ? xcd * (q + 1) + cidx
                               : r8 * (q + 1) + (xcd - r8) * q + cidx;
    const int bx = swz / NTT, by = swz % NTT;
    const int brow = bx * BM, bcol = by * BM;

    // hoisted stage addressing (invariant across j and t)
    const int p     = wave * 2048 + lane * 16;
    const int srow  = p >> 6;
    const int schk  = ((p >> 4) & 3) ^ ((srow >> 1) & 3);
    const char* gAp = (const char*)Abf + (size_t)(brow + srow) * 512 + (schk << 4);
    const char* gBp = (const char*)Bbf + (size_t)(bcol + srow) * 512 + (schk << 4);

#define GLDS(gp, lp) __builtin_amdgcn_global_load_lds( \
    (const __attribute__((address_space(1))) unsigned int*)(gp), \
    (__attribute__((address_space(3))) unsigned int*)(lp), 16, 0, 0)

#define STAGE(T) {                                                      \
    char* db_ = lds + ((T) & 1) * BUFB + wave * 2048;                   \
    GLDS(gAp + (T) * 64,        db_);                                   \
    GLDS(gAp + (T) * 64 + 8192, db_ + 1024);                            \
    GLDS(gBp + (T) * 64,        db_ + MATB);                            \
    GLDS(gBp + (T) * 64 + 8192, db_ + MATB + 1024);                     \
}

    const int wr = wave >> 1;   // 0..1  -> m block of 64 rows
    const int wc = wave & 1;    // 0..1  -> n block of 64 cols
    const int lr = lane & 15;
    const int lg = lane >> 4;   // 0..3 = K chunk (8 bf16 each)

    int aoff[4], boff[4];
    #pragma unroll
    for (int m = 0; m < 4; ++m) {
        int r = wr * 64 + m * 16 + lr;
        aoff[m] = r * 64 + ((lg ^ ((r >> 1) & 3)) << 4);
    }
    #pragma unroll
    for (int n = 0; n < 4; ++n) {
        int r = wc * 64 + n * 16 + lr;
        boff[n] = MATB + r * 64 + ((lg ^ ((r >> 1) & 3)) << 4);
    }

    f32x4 acc[4][4] = {};

    STAGE(0);
    #pragma unroll
    for (int t = 0; t < NKT; ++t) {
        __syncthreads();                 // drains stage(t); buf[(t+1)&1] reads retired
        if (t + 1 < NKT) STAGE(t + 1);   // issue early; hides under compute(t)
        const char* base = lds + (t & 1) * BUFB;
        bf16x8 a[4], b[4];
        #pragma unroll
        for (int m = 0; m < 4; ++m)
            a[m] = *reinterpret_cast<const bf16x8*>(base + aoff[m]);
        #pragma unroll
        for (int n = 0; n < 4; ++n)
            b[n] = *reinterpret_cast<const bf16x8*>(base + boff[n]);
        #pragma unroll
        for (int m = 0; m < 4; ++m)
            #pragma unroll
            for (int n = 0; n < 4; ++n)
                acc[m][n] = __builtin_amdgcn_mfma_f32_16x16x32_bf16(a[m], b[n], acc[m][n], 0, 0, 0);
    }
#undef GLDS
#undef STAGE

    // ---- fused reductions. C/D: col = lane&15, row = (lane>>4)*4 + reg ----
    float mx = -3.4e38f;
    float cs[4] = {0.f, 0.f, 0.f, 0.f};
    float rs[16];
    #pragma unroll
    for (int j = 0; j < 16; ++j) rs[j] = 0.0f;
    #pragma unroll
    for (int m = 0; m < 4; ++m)
        #pragma unroll
        for (int n = 0; n < 4; ++n)
            #pragma unroll
            for (int r = 0; r < 4; ++r) {
                float v = acc[m][n][r];
                mx = fmaxf(mx, v);
                float rv = fmaxf(v, 0.0f);
                cs[n] += rv;
                rs[m * 4 + r] += rv;
            }

    // col sums -> 16 lane-resident values per wave
    #pragma unroll
    for (int n = 0; n < 4; ++n) {
        cs[n] += __shfl_xor(cs[n], 16);
        cs[n] += __shfl_xor(cs[n], 32);
    }
    // row sums -> lanes with lr==0 hold 16 values each
    #pragma unroll
    for (int off = 1; off <= 8; off <<= 1)
        #pragma unroll
        for (int j = 0; j < 16; ++j)
            rs[j] += __shfl_xor(rs[j], off);
    // wave max
    #pragma unroll
    for (int off = 32; off >= 1; off >>= 1)
        mx = fmaxf(mx, __shfl_xor(mx, off));

    __syncthreads();                     // all LDS tile reads retired -> reuse
    float* rowpart = (float*)lds;              // [4][64]
    float* colpart = (float*)(lds + 1024);     // [4][64]
    float* wmaxs   = (float*)(lds + 2048);     // [4]

    if (lr == 0) {                       // 4 lanes/wave (lg=0..3)
        #pragma unroll
        for (int m = 0; m < 4; ++m)
            #pragma unroll
            for (int r = 0; r < 4; ++r)
                rowpart[wave * 64 + m * 16 + lg * 4 + r] = rs[m * 4 + r];
    }
    if (lane < 16) {
        #pragma unroll
        for (int n = 0; n < 4; ++n)
            colpart[wave * 64 + n * 16 + lane] = cs[n];
    }
    if (lane == 0) wmaxs[wave] = mx;
    __syncthreads();

    if (tid < 128) {
        // rows brow+tid: waves (row>>6)*2 + {0,1} share this row range
        int rhi = tid >> 6, rlo = tid & 63;
        float s = rowpart[(rhi * 2 + 0) * 64 + rlo] + rowpart[(rhi * 2 + 1) * 64 + rlo];
        partial_row[(size_t)by * NPAD + brow + tid] = s;
    } else if (tid < 256) {
        // cols bcol+(tid-128): waves (col>>6) + {0,2} share this col range
        int i = tid - 128;
        int chi = i >> 6, clo = i & 63;
        float s = colpart[(chi + 0) * 64 + clo] + colpart[(chi + 2) * 64 + clo];
        partial_col[(size_t)bx * NPAD + bcol + i] = s;
    }
    if (tid == 0)
        blk_max[wg] = fmaxf(fmaxf(wmaxs[0], wmaxs[1]), fmaxf(wmaxs[2], wmaxs[3]));
}

// Fold the 42 partial strips per row/col; block 42 reduces the 1764 maxes.
__global__ void reduce_partials(const float* __restrict__ pr, const float* __restrict__ pc,
                                const float* __restrict__ bm,
                                float* __restrict__ row_sum, float* __restrict__ col_sum,
                                float* __restrict__ maxv) {
    if (blockIdx.x < 42) {
        int i = blockIdx.x * 256 + threadIdx.x;  // 0..10751 over row+col
        float s = 0.f;
        if (i < NPAD) {
            #pragma unroll
            for (int j = 0; j < NTT; ++j) s += pr[(size_t)j * NPAD + i];
            row_sum[i] = s;
        } else {
            int c = i - NPAD;
            #pragma unroll
            for (int j = 0; j < NTT; ++j) s += pc[(size_t)j * NPAD + c];
            col_sum[c] = s;
        }
    } else {
        __shared__ float sm[256];
        int t = threadIdx.x;
        float m = -3.4e38f;
        for (int j = t; j < NWG; j += 256) m = fmaxf(m, bm[j]);
        sm[t] = m;
        __syncthreads();
        #pragma unroll
        for (int s = 128; s >= 1; s >>= 1) {
            if (t < s) sm[t] = fmaxf(sm[t], sm[t + s]);
            __syncthreads();
        }
        if (t == 0) maxv[0] = sm[0];
    }
}

// Bilinear resize 2x72x72 -> 2x224x224 with final /max (resize is linear).
__global__ void finalize(const float* __restrict__ row_sum,
                         const float* __restrict__ col_sum,
                         const float* __restrict__ maxv,
                         float* __restrict__ out) {
    int o = blockIdx.x * blockDim.x + threadIdx.x;
    if (o >= 2 * OUTHW * OUTHW) return;
    int img = o / (OUTHW * OUTHW);
    int rem = o % (OUTHW * OUTHW);
    int oy = rem / OUTHW, ox = rem % OUTHW;
    const float* src = (img == 0) ? row_sum : col_sum;
    float inv = 1.0f / maxv[0];

    const float s = 72.0f / 224.0f;
    float ys = fmaxf(((float)oy + 0.5f) * s - 0.5f, 0.0f);
    float xs = fmaxf(((float)ox + 0.5f) * s - 0.5f, 0.0f);
    int y0 = (int)floorf(ys), x0 = (int)floorf(xs);
    int y1 = min(y0 + 1, 71), x1 = min(x0 + 1, 71);
    float wy = ys - (float)y0, wx = xs - (float)x0;

    float a = src[y0 * 72 + x0], b = src[y0 * 72 + x1];
    float c = src[y1 * 72 + x0], d = src[y1 * 72 + x1];
    float v = a * (1.0f - wy) * (1.0f - wx) + b * (1.0f - wy) * wx
            + c * wy * (1.0f - wx)          + d * wy * wx;
    out[o] = v * inv;
}

extern "C" void kernel_launch(void* const* d_in, const int* in_sizes, int n_in,
                              void* d_out, int out_size, void* d_ws, size_t ws_size,
                              hipStream_t stream) {
    const float* X = (const float*)d_in[0];
    float* out = (float*)d_out;

    unsigned short* Abf = (unsigned short*)d_ws;
    unsigned short* Bbf = Abf + (size_t)NPAD * KDIM;
    float* partial_row  = (float*)(Bbf + (size_t)NPAD * KDIM);
    float* partial_col  = partial_row + (size_t)NTT * NPAD;
    float* blk_max      = partial_col + (size_t)NTT * NPAD;
    float* row_sum      = blk_max + NWG;
    float* col_sum      = row_sum + NPAD;
    float* maxv         = col_sum + NPAD;

    int nthr = 2 * NPAD * (KDIM / 8);
    convert_pad_bf16<<<(nthr + 255) / 256, 256, 0, stream>>>(X, Abf, Bbf);
    gemm_reduce<<<NWG, 256, 0, stream>>>(Abf, Bbf, partial_row, partial_col, blk_max);
    reduce_partials<<<43, 256, 0, stream>>>(partial_row, partial_col, blk_max,
                                            row_sum, col_sum, maxv);
    finalize<<<(2 * OUTHW * OUTHW + 255) / 256, 256, 0, stream>>>(row_sum, col_sum, maxv, out);
}